// Round 1
// baseline (256.393 us; speedup 1.0000x reference)
//
#include <hip/hip_runtime.h>
#include <hip/hip_bf16.h>

typedef __bf16 bf16;
typedef bf16 bf16x8 __attribute__((ext_vector_type(8)));
typedef float f32x4 __attribute__((ext_vector_type(4)));

constexpr int LL = 1024;   // sequence length
constexpr int EE = 512;    // embed dim
constexpr int NBATCH = 8;

__device__ __forceinline__ f32x4 mfma16(bf16x8 a, bf16x8 b, f32x4 c) {
    return __builtin_amdgcn_mfma_f32_16x16x32_bf16(a, b, c, 0, 0, 0);
}

struct ProjParams {
    const float* x[4];
    const float* w[4];
    const float* b[4];
};

// ---------------------------------------------------------------------------
// Projection: O[z] = bf16( X[z] @ W[z]^T + b[z] ), X:[8192,512] f32, W:[512,512] f32
// 128x128 tile, BK=32, 256 threads (4 waves, 2x2, each wave 64x64 via 4x4 mfma)
// ---------------------------------------------------------------------------
__global__ __launch_bounds__(256) void proj_kernel(ProjParams p, bf16* __restrict__ outbase) {
    const int z = blockIdx.z;
    const float* __restrict__ X = p.x[z];
    const float* __restrict__ W = p.w[z];
    const float* __restrict__ Bv = p.b[z];
    bf16* __restrict__ O = outbase + (size_t)z * (NBATCH * LL) * EE;

    __shared__ alignas(16) bf16 As[128][40];  // padded stride 40 (80B) breaks bank conflicts
    __shared__ alignas(16) bf16 Bs[128][40];

    const int t = threadIdx.x;
    const int lane = t & 63, wid = t >> 6;
    const int wm = wid & 1, wn = wid >> 1;
    const int lr = lane & 15, kg = lane >> 4;
    const int bx = blockIdx.x, by = blockIdx.y;

    f32x4 acc[4][4] = {};

    const int col4 = (t & 7) * 4;  // f32 column group within BK=32
    const int row0 = t >> 3;       // 0..31

    for (int k0 = 0; k0 < EE; k0 += 32) {
#pragma unroll
        for (int i = 0; i < 4; ++i) {
            const int r = row0 + 32 * i;
            float4 a = *(const float4*)(X + (size_t)(by * 128 + r) * EE + k0 + col4);
            As[r][col4 + 0] = (bf16)a.x; As[r][col4 + 1] = (bf16)a.y;
            As[r][col4 + 2] = (bf16)a.z; As[r][col4 + 3] = (bf16)a.w;
            float4 b = *(const float4*)(W + (size_t)(bx * 128 + r) * EE + k0 + col4);
            Bs[r][col4 + 0] = (bf16)b.x; Bs[r][col4 + 1] = (bf16)b.y;
            Bs[r][col4 + 2] = (bf16)b.z; Bs[r][col4 + 3] = (bf16)b.w;
        }
        __syncthreads();
        bf16x8 af[4], bfr[4];
#pragma unroll
        for (int im = 0; im < 4; ++im)
            af[im] = *(const bf16x8*)&As[wm * 64 + im * 16 + lr][kg * 8];
#pragma unroll
        for (int in = 0; in < 4; ++in)
            bfr[in] = *(const bf16x8*)&Bs[wn * 64 + in * 16 + lr][kg * 8];
#pragma unroll
        for (int im = 0; im < 4; ++im)
#pragma unroll
            for (int in = 0; in < 4; ++in)
                acc[im][in] = mfma16(af[im], bfr[in], acc[im][in]);
        __syncthreads();
    }

    // C/D layout (16x16x32 bf16): col = lane&15, row = (lane>>4)*4 + reg  [m89-verified]
#pragma unroll
    for (int im = 0; im < 4; ++im) {
        const int row = by * 128 + wm * 64 + im * 16 + kg * 4;
#pragma unroll
        for (int in = 0; in < 4; ++in) {
            const int col = bx * 128 + wn * 64 + in * 16 + lr;
            const float bias = Bv[col];
#pragma unroll
            for (int r = 0; r < 4; ++r)
                O[(size_t)(row + r) * EE + col] = (bf16)(acc[im][in][r] + bias);
        }
    }
}

// ---------------------------------------------------------------------------
// Scores: S[n] = (Q[n] @ K[n]^T) * inv_scale, per-batch 1024x1024, fp32 out
// grid (8,8,8): x=col tile, y=row tile, z=batch
// ---------------------------------------------------------------------------
__global__ __launch_bounds__(256) void scores_kernel(const bf16* __restrict__ Q,
                                                     const bf16* __restrict__ Kt,
                                                     float* __restrict__ S) {
    const int n = blockIdx.z;
    const bf16* __restrict__ Qb = Q + (size_t)n * LL * EE;
    const bf16* __restrict__ Kb = Kt + (size_t)n * LL * EE;
    float* __restrict__ Sb = S + (size_t)n * LL * LL;

    __shared__ alignas(16) bf16 As[128][40];
    __shared__ alignas(16) bf16 Bs[128][40];

    const int t = threadIdx.x;
    const int lane = t & 63, wid = t >> 6;
    const int wm = wid & 1, wn = wid >> 1;
    const int lr = lane & 15, kg = lane >> 4;
    const int bx = blockIdx.x, by = blockIdx.y;

    f32x4 acc[4][4] = {};

    const int colg = (t & 3) * 8;  // bf16 column group (8 elems = 16B)
    const int row0 = t >> 2;       // 0..63

    for (int k0 = 0; k0 < EE; k0 += 32) {
#pragma unroll
        for (int i = 0; i < 2; ++i) {
            const int r = row0 + 64 * i;
            uint4 qa = *(const uint4*)(Qb + (size_t)(by * 128 + r) * EE + k0 + colg);
            *(uint4*)&As[r][colg] = qa;
            uint4 kb = *(const uint4*)(Kb + (size_t)(bx * 128 + r) * EE + k0 + colg);
            *(uint4*)&Bs[r][colg] = kb;
        }
        __syncthreads();
        bf16x8 af[4], bfr[4];
#pragma unroll
        for (int im = 0; im < 4; ++im)
            af[im] = *(const bf16x8*)&As[wm * 64 + im * 16 + lr][kg * 8];
#pragma unroll
        for (int in = 0; in < 4; ++in)
            bfr[in] = *(const bf16x8*)&Bs[wn * 64 + in * 16 + lr][kg * 8];
#pragma unroll
        for (int im = 0; im < 4; ++im)
#pragma unroll
            for (int in = 0; in < 4; ++in)
                acc[im][in] = mfma16(af[im], bfr[in], acc[im][in]);
        __syncthreads();
    }

    const float inv_scale = 0.011048543456039806f;  // 1/(4*sqrt(512))
#pragma unroll
    for (int im = 0; im < 4; ++im) {
        const int row = by * 128 + wm * 64 + im * 16 + kg * 4;
#pragma unroll
        for (int in = 0; in < 4; ++in) {
            const int col = bx * 128 + wn * 64 + in * 16 + lr;
#pragma unroll
            for (int r = 0; r < 4; ++r)
                Sb[(size_t)(row + r) * LL + col] = acc[im][in][r] * inv_scale;
        }
    }
}

// ---------------------------------------------------------------------------
// Softmax over each row (length 1024) for each of 8 batches, mean over batches,
// write to the correct quadrant of the 2048x2048 output.
// grid: 1024 blocks (one per q row), 256 threads (4 cols/thread)
// ---------------------------------------------------------------------------
__global__ __launch_bounds__(256) void softmax_mean_kernel(const float* __restrict__ S,
                                                           float* __restrict__ out,
                                                           int mapIdx) {
    const int q = blockIdx.x;
    const int t = threadIdx.x;
    const int lane = t & 63, wid = t >> 6;
    __shared__ float red[4];

    float acc0 = 0.f, acc1 = 0.f, acc2 = 0.f, acc3 = 0.f;

    for (int n = 0; n < NBATCH; ++n) {
        float4 v = *(const float4*)(S + ((size_t)n * LL + q) * LL + t * 4);
        float mx = fmaxf(fmaxf(v.x, v.y), fmaxf(v.z, v.w));
#pragma unroll
        for (int off = 32; off; off >>= 1) mx = fmaxf(mx, __shfl_xor(mx, off));
        if (lane == 0) red[wid] = mx;
        __syncthreads();
        mx = fmaxf(fmaxf(red[0], red[1]), fmaxf(red[2], red[3]));
        __syncthreads();
        float e0 = __expf(v.x - mx), e1 = __expf(v.y - mx);
        float e2 = __expf(v.z - mx), e3 = __expf(v.w - mx);
        float s = e0 + e1 + e2 + e3;
#pragma unroll
        for (int off = 32; off; off >>= 1) s += __shfl_xor(s, off);
        if (lane == 0) red[wid] = s;
        __syncthreads();
        s = red[0] + red[1] + red[2] + red[3];
        __syncthreads();
        const float inv = 1.0f / s;
        acc0 += e0 * inv; acc1 += e1 * inv; acc2 += e2 * inv; acc3 += e3 * inv;
    }

    const int orow = (mapIdx >= 2 ? LL : 0) + q;
    const int ocol = (mapIdx & 1 ? LL : 0) + t * 4;
    float4 o = make_float4(acc0 * 0.125f, acc1 * 0.125f, acc2 * 0.125f, acc3 * 0.125f);
    *(float4*)(out + (size_t)orow * (2 * LL) + ocol) = o;
}

// ---------------------------------------------------------------------------
extern "C" void kernel_launch(void* const* d_in, const int* in_sizes, int n_in,
                              void* d_out, int out_size, void* d_ws, size_t ws_size,
                              hipStream_t stream) {
    const float* modalA = (const float*)d_in[0];
    const float* modalB = (const float*)d_in[1];
    const float* WqA = (const float*)d_in[2];
    const float* bqA = (const float*)d_in[3];
    const float* WkA = (const float*)d_in[4];
    const float* bkA = (const float*)d_in[5];
    const float* WqB = (const float*)d_in[6];
    const float* bqB = (const float*)d_in[7];
    const float* WkB = (const float*)d_in[8];
    const float* bkB = (const float*)d_in[9];
    float* out = (float*)d_out;

    // ws layout: [4 x 8192x512 bf16 projections | 8x1024x1024 f32 score buffer]
    bf16* qk = (bf16*)d_ws;
    float* S = (float*)((char*)d_ws + (size_t)4 * (NBATCH * LL) * EE * sizeof(bf16));

    ProjParams pp;
    pp.x[0] = modalA; pp.x[1] = modalA; pp.x[2] = modalB; pp.x[3] = modalB;
    pp.w[0] = WqA; pp.w[1] = WkA; pp.w[2] = WqB; pp.w[3] = WkB;
    pp.b[0] = bqA; pp.b[1] = bkA; pp.b[2] = bqB; pp.b[3] = bkB;

    proj_kernel<<<dim3(4, 64, 4), 256, 0, stream>>>(pp, qk);

    const bf16* qA = qk + (size_t)0 * (NBATCH * LL) * EE;
    const bf16* kA = qk + (size_t)1 * (NBATCH * LL) * EE;
    const bf16* qB = qk + (size_t)2 * (NBATCH * LL) * EE;
    const bf16* kB = qk + (size_t)3 * (NBATCH * LL) * EE;

    // map order: 0=(qA,kA)->TL, 1=(qA,kB)->TR, 2=(qB,kB)->BL, 3=(qB,kA)->BR
    const bf16* QM[4] = {qA, qA, qB, qB};
    const bf16* KM[4] = {kA, kB, kB, kA};
    for (int m = 0; m < 4; ++m) {
        scores_kernel<<<dim3(8, 8, 8), 256, 0, stream>>>(QM[m], KM[m], S);
        softmax_mean_kernel<<<dim3(1024), 256, 0, stream>>>(S, out, m);
    }
}

// Round 2
// 228.011 us; speedup vs baseline: 1.1245x; 1.1245x over previous
//
#include <hip/hip_runtime.h>
#include <hip/hip_bf16.h>

typedef __bf16 bf16;
typedef bf16 bf16x8 __attribute__((ext_vector_type(8)));
typedef bf16 bf16x4v __attribute__((ext_vector_type(4)));
typedef _Float16 f16;
typedef f16 f16x4 __attribute__((ext_vector_type(4)));
typedef float f32x4 __attribute__((ext_vector_type(4)));

constexpr int LL = 1024;   // sequence length
constexpr int EE = 512;    // embed dim
constexpr int NBATCH = 8;

__device__ __forceinline__ f32x4 mfma16(bf16x8 a, bf16x8 b, f32x4 c) {
    return __builtin_amdgcn_mfma_f32_16x16x32_bf16(a, b, c, 0, 0, 0);
}

// global -> LDS direct DMA, 16B per lane. LDS dest must be wave-uniform base
// + lane*16 — our staging addresses are exactly linear in t*16 (unpadded tile).
#define GLOAD_LDS16(g, l)                                                     \
    __builtin_amdgcn_global_load_lds(                                         \
        (const __attribute__((address_space(1))) void*)(g),                   \
        (__attribute__((address_space(3))) void*)(l), 16, 0, 0)

// ---------------------------------------------------------------------------
// fp32 -> bf16 conversion for modalA, modalB, and the 4 weight matrices.
// grid (blocks, 6): y selects tensor, grid-stride within.
// ---------------------------------------------------------------------------
struct CvtParams {
    const float* src[6];
    bf16* dst[6];
    int n4[6];  // element count / 4
};

__global__ __launch_bounds__(256) void cvt_kernel(CvtParams p) {
    const int y = blockIdx.y;
    const float* __restrict__ src = p.src[y];
    bf16* __restrict__ dst = p.dst[y];
    const int n4 = p.n4[y];
    for (int i = blockIdx.x * 256 + threadIdx.x; i < n4; i += gridDim.x * 256) {
        float4 v = *(const float4*)(src + (size_t)i * 4);
        bf16x4v o;
        o[0] = (bf16)v.x; o[1] = (bf16)v.y; o[2] = (bf16)v.z; o[3] = (bf16)v.w;
        *(bf16x4v*)(dst + (size_t)i * 4) = o;
    }
}

// ---------------------------------------------------------------------------
// Projection: O[z] = bf16( X[z] @ W[z]^T + b[z] ), all bf16, NT GEMM.
// 128x128 tile, BK=32, m97-style global_load_lds staging.
// grid (4, 64, 4): x = N tile, y = M tile, z = which projection.
// ---------------------------------------------------------------------------
struct ProjParams {
    const bf16* x[4];
    const bf16* w[4];
    const float* b[4];
};

__global__ __launch_bounds__(256) void proj_kernel(ProjParams p, bf16* __restrict__ outbase) {
    const int z = blockIdx.z;
    const bf16* __restrict__ X = p.x[z];
    const bf16* __restrict__ W = p.w[z];
    const float* __restrict__ Bv = p.b[z];
    bf16* __restrict__ O = outbase + (size_t)z * (NBATCH * LL) * EE;

    __shared__ alignas(16) bf16 As[128][32];  // unpadded: required by global_load_lds
    __shared__ alignas(16) bf16 Bs[128][32];

    const int t = threadIdx.x;
    const int lane = t & 63, wid = t >> 6;
    const int wm = wid & 1, wn = wid >> 1;
    const int lr = lane & 15, kg = lane >> 4;
    const int bx = blockIdx.x, by = blockIdx.y;

    f32x4 acc[4][4] = {};

    const int srow = t >> 2;        // 0..63
    const int scol = (t & 3) * 8;   // bf16 col group (16 B)

    for (int k0 = 0; k0 < EE; k0 += 32) {
#pragma unroll
        for (int i = 0; i < 2; ++i) {
            const int r = srow + 64 * i;
            GLOAD_LDS16(X + (size_t)(by * 128 + r) * EE + k0 + scol, &As[r][scol]);
            GLOAD_LDS16(W + (size_t)(bx * 128 + r) * EE + k0 + scol, &Bs[r][scol]);
        }
        __builtin_amdgcn_s_waitcnt(0);
        __syncthreads();
        bf16x8 af[4], bfr[4];
#pragma unroll
        for (int im = 0; im < 4; ++im)
            af[im] = *(const bf16x8*)&As[wm * 64 + im * 16 + lr][kg * 8];
#pragma unroll
        for (int in = 0; in < 4; ++in)
            bfr[in] = *(const bf16x8*)&Bs[wn * 64 + in * 16 + lr][kg * 8];
#pragma unroll
        for (int im = 0; im < 4; ++im)
#pragma unroll
            for (int in = 0; in < 4; ++in)
                acc[im][in] = mfma16(af[im], bfr[in], acc[im][in]);
        __syncthreads();
    }

    // C/D layout (16x16x32 bf16): col = lane&15, row = (lane>>4)*4 + reg  [m89]
#pragma unroll
    for (int im = 0; im < 4; ++im) {
        const int row = by * 128 + wm * 64 + im * 16 + kg * 4;
#pragma unroll
        for (int in = 0; in < 4; ++in) {
            const int col = bx * 128 + wn * 64 + in * 16 + lr;
            const float bias = Bv[col];
#pragma unroll
            for (int r = 0; r < 4; ++r)
                O[(size_t)(row + r) * EE + col] = (bf16)(acc[im][in][r] + bias);
        }
    }
}

// ---------------------------------------------------------------------------
// Scores: S[n] = f16( (Q[n] @ K[n]^T) * inv_scale ), per-batch 1024x1024.
// grid (8, 8, 8): x = col tile, y = row tile, z = batch.
// ---------------------------------------------------------------------------
__global__ __launch_bounds__(256) void scores_kernel(const bf16* __restrict__ Q,
                                                     const bf16* __restrict__ Kt,
                                                     f16* __restrict__ S) {
    const int n = blockIdx.z;
    const bf16* __restrict__ Qb = Q + (size_t)n * LL * EE;
    const bf16* __restrict__ Kb = Kt + (size_t)n * LL * EE;
    f16* __restrict__ Sb = S + (size_t)n * LL * LL;

    __shared__ alignas(16) bf16 As[128][32];
    __shared__ alignas(16) bf16 Bs[128][32];

    const int t = threadIdx.x;
    const int lane = t & 63, wid = t >> 6;
    const int wm = wid & 1, wn = wid >> 1;
    const int lr = lane & 15, kg = lane >> 4;
    const int bx = blockIdx.x, by = blockIdx.y;

    f32x4 acc[4][4] = {};

    const int srow = t >> 2;
    const int scol = (t & 3) * 8;

    for (int k0 = 0; k0 < EE; k0 += 32) {
#pragma unroll
        for (int i = 0; i < 2; ++i) {
            const int r = srow + 64 * i;
            GLOAD_LDS16(Qb + (size_t)(by * 128 + r) * EE + k0 + scol, &As[r][scol]);
            GLOAD_LDS16(Kb + (size_t)(bx * 128 + r) * EE + k0 + scol, &Bs[r][scol]);
        }
        __builtin_amdgcn_s_waitcnt(0);
        __syncthreads();
        bf16x8 af[4], bfr[4];
#pragma unroll
        for (int im = 0; im < 4; ++im)
            af[im] = *(const bf16x8*)&As[wm * 64 + im * 16 + lr][kg * 8];
#pragma unroll
        for (int in = 0; in < 4; ++in)
            bfr[in] = *(const bf16x8*)&Bs[wn * 64 + in * 16 + lr][kg * 8];
#pragma unroll
        for (int im = 0; im < 4; ++im)
#pragma unroll
            for (int in = 0; in < 4; ++in)
                acc[im][in] = mfma16(af[im], bfr[in], acc[im][in]);
        __syncthreads();
    }

    const float inv_scale = 0.011048543456039806f;  // 1/(4*sqrt(512))
#pragma unroll
    for (int im = 0; im < 4; ++im) {
        const int row = by * 128 + wm * 64 + im * 16 + kg * 4;
#pragma unroll
        for (int in = 0; in < 4; ++in) {
            const int col = bx * 128 + wn * 64 + in * 16 + lr;
#pragma unroll
            for (int r = 0; r < 4; ++r)
                Sb[(size_t)(row + r) * LL + col] = (f16)(acc[im][in][r] * inv_scale);
        }
    }
}

// ---------------------------------------------------------------------------
// Row softmax (length 1024, f16 in) for 8 batches, mean over batches, write
// one 1024x1024 quadrant of the 2048x2048 fp32 output.
// No max-subtraction: |S| <~ 2 (sigma ~0.25), exp is exact-safe in fp32.
// grid: 1024 blocks (one per q row), 256 threads (4 cols each).
// ---------------------------------------------------------------------------
__global__ __launch_bounds__(256) void softmax_mean_kernel(const f16* __restrict__ S,
                                                           float* __restrict__ out,
                                                           int mapIdx) {
    const int q = blockIdx.x;
    const int t = threadIdx.x;
    const int lane = t & 63, wid = t >> 6;
    __shared__ float red[NBATCH][4];

    f16x4 v[NBATCH];
#pragma unroll
    for (int n = 0; n < NBATCH; ++n)
        v[n] = *(const f16x4*)(S + ((size_t)n * LL + q) * LL + t * 4);

    float e[NBATCH][4];
#pragma unroll
    for (int n = 0; n < NBATCH; ++n) {
        float s = 0.f;
#pragma unroll
        for (int j = 0; j < 4; ++j) {
            e[n][j] = __expf((float)v[n][j]);
            s += e[n][j];
        }
#pragma unroll
        for (int off = 32; off; off >>= 1) s += __shfl_xor(s, off);
        if (lane == 0) red[n][wid] = s;
    }
    __syncthreads();

    float acc[4] = {};
#pragma unroll
    for (int n = 0; n < NBATCH; ++n) {
        const float inv = 1.0f / (red[n][0] + red[n][1] + red[n][2] + red[n][3]);
#pragma unroll
        for (int j = 0; j < 4; ++j) acc[j] += e[n][j] * inv;
    }

    const int orow = (mapIdx >= 2 ? LL : 0) + q;
    const int ocol = (mapIdx & 1 ? LL : 0) + t * 4;
    float4 o = make_float4(acc[0] * 0.125f, acc[1] * 0.125f, acc[2] * 0.125f, acc[3] * 0.125f);
    *(float4*)(out + (size_t)orow * (2 * LL) + ocol) = o;
}

// ---------------------------------------------------------------------------
extern "C" void kernel_launch(void* const* d_in, const int* in_sizes, int n_in,
                              void* d_out, int out_size, void* d_ws, size_t ws_size,
                              hipStream_t stream) {
    const float* modalA = (const float*)d_in[0];
    const float* modalB = (const float*)d_in[1];
    const float* WqA = (const float*)d_in[2];
    const float* bqA = (const float*)d_in[3];
    const float* WkA = (const float*)d_in[4];
    const float* bkA = (const float*)d_in[5];
    const float* WqB = (const float*)d_in[6];
    const float* bqB = (const float*)d_in[7];
    const float* WkB = (const float*)d_in[8];
    const float* bkB = (const float*)d_in[9];
    float* out = (float*)d_out;

    // ws layout (52.4 MB):
    //   [qk: 4 x 8192x512 bf16 = 33.55 MB]
    //   [region2: XA/XB/W4 bf16 (18.9 MB) -- later overlapped by S f16 (16.8 MB)]
    // XA/XB/W4 are dead after proj_kernel; S is written after it. Stream-ordered.
    const size_t projN = (size_t)(NBATCH * LL) * EE;       // 4 Mi elems
    char* base = (char*)d_ws;
    bf16* qk = (bf16*)base;
    char* region2 = base + 4 * projN * sizeof(bf16);
    bf16* XA = (bf16*)region2;
    bf16* XB = XA + projN;
    bf16* W4 = XB + projN;                                  // 4 x 512x512
    f16* S = (f16*)region2;

    CvtParams cp;
    cp.src[0] = modalA; cp.dst[0] = XA; cp.n4[0] = (int)(projN / 4);
    cp.src[1] = modalB; cp.dst[1] = XB; cp.n4[1] = (int)(projN / 4);
    const float* ws[4] = {WqA, WkA, WqB, WkB};
    for (int i = 0; i < 4; ++i) {
        cp.src[2 + i] = ws[i];
        cp.dst[2 + i] = W4 + (size_t)i * EE * EE;
        cp.n4[2 + i] = EE * EE / 4;
    }
    cvt_kernel<<<dim3(1024, 6), 256, 0, stream>>>(cp);

    ProjParams pp;
    pp.x[0] = XA; pp.x[1] = XA; pp.x[2] = XB; pp.x[3] = XB;
    for (int i = 0; i < 4; ++i) pp.w[i] = W4 + (size_t)i * EE * EE;
    pp.b[0] = bqA; pp.b[1] = bkA; pp.b[2] = bqB; pp.b[3] = bkB;
    proj_kernel<<<dim3(4, 64, 4), 256, 0, stream>>>(pp, qk);

    const bf16* qA = qk + 0 * projN;
    const bf16* kA = qk + 1 * projN;
    const bf16* qB = qk + 2 * projN;
    const bf16* kB = qk + 3 * projN;

    // map order: 0=(qA,kA)->TL, 1=(qA,kB)->TR, 2=(qB,kB)->BL, 3=(qB,kA)->BR
    const bf16* QM[4] = {qA, qA, qB, qB};
    const bf16* KM[4] = {kA, kB, kB, kA};
    for (int m = 0; m < 4; ++m) {
        scores_kernel<<<dim3(8, 8, 8), 256, 0, stream>>>(QM[m], KM[m], S);
        softmax_mean_kernel<<<dim3(1024), 256, 0, stream>>>(S, out, m);
    }
}

// Round 3
// 202.771 us; speedup vs baseline: 1.2644x; 1.1245x over previous
//
#include <hip/hip_runtime.h>
#include <hip/hip_bf16.h>

typedef __bf16 bf16;
typedef bf16 bf16x8 __attribute__((ext_vector_type(8)));
typedef bf16 bf16x4v __attribute__((ext_vector_type(4)));
typedef _Float16 f16;
typedef f16 f16x4 __attribute__((ext_vector_type(4)));
typedef float f32x4 __attribute__((ext_vector_type(4)));

constexpr int LL = 1024;   // sequence length
constexpr int EE = 512;    // embed dim
constexpr int NBATCH = 8;

__device__ __forceinline__ f32x4 mfma16(bf16x8 a, bf16x8 b, f32x4 c) {
    return __builtin_amdgcn_mfma_f32_16x16x32_bf16(a, b, c, 0, 0, 0);
}

// global -> LDS direct DMA, 16B per lane; LDS dest = wave-uniform base + lane*16.
#define GLOAD_LDS16(g, l)                                                     \
    __builtin_amdgcn_global_load_lds(                                         \
        (const __attribute__((address_space(1))) void*)(g),                   \
        (__attribute__((address_space(3))) void*)(l), 16, 0, 0)

// ---------------------------------------------------------------------------
// fp32 -> bf16 conversion for modalA, modalB, and the 4 weight matrices.
// ---------------------------------------------------------------------------
struct CvtParams {
    const float* src[6];
    bf16* dst[6];
    int n4[6];  // element count / 4
};

__global__ __launch_bounds__(256) void cvt_kernel(CvtParams p) {
    const int y = blockIdx.y;
    const float* __restrict__ src = p.src[y];
    bf16* __restrict__ dst = p.dst[y];
    const int n4 = p.n4[y];
    for (int i = blockIdx.x * 256 + threadIdx.x; i < n4; i += gridDim.x * 256) {
        float4 v = *(const float4*)(src + (size_t)i * 4);
        bf16x4v o;
        o[0] = (bf16)v.x; o[1] = (bf16)v.y; o[2] = (bf16)v.z; o[3] = (bf16)v.w;
        *(bf16x4v*)(dst + (size_t)i * 4) = o;
    }
}

// ---------------------------------------------------------------------------
// Projection: O[z] = bf16( X[z] @ W[z]^T + b[z] ), bf16 NT GEMM, 128x128 tile,
// BK=32, m97 staging, LDS-repack epilogue for coalesced stores.
// grid (4, 64, 4): x = N tile, y = M tile, z = which projection.
// ---------------------------------------------------------------------------
struct ProjParams {
    const bf16* x[4];
    const bf16* w[4];
    const float* b[4];
};

__global__ __launch_bounds__(256) void proj_kernel(ProjParams p, bf16* __restrict__ outbase) {
    const int z = blockIdx.z;
    const bf16* __restrict__ X = p.x[z];
    const bf16* __restrict__ W = p.w[z];
    const float* __restrict__ Bv = p.b[z];
    bf16* __restrict__ O = outbase + (size_t)z * (NBATCH * LL) * EE;

    __shared__ union {
        struct { alignas(16) bf16 A[128][32]; alignas(16) bf16 B[128][32]; } st;
        alignas(16) bf16 ep[128][140];  // stride 140: conflict-free epilogue writes
    } sm;

    const int t = threadIdx.x;
    const int lane = t & 63, wid = t >> 6;
    const int wm = wid & 1, wn = wid >> 1;
    const int lr = lane & 15, kg = lane >> 4;
    const int bx = blockIdx.x, by = blockIdx.y;

    f32x4 acc[4][4] = {};

    const int srow = t >> 2;        // 0..63
    const int scol = (t & 3) * 8;   // bf16 col group (16 B)

    for (int k0 = 0; k0 < EE; k0 += 32) {
#pragma unroll
        for (int i = 0; i < 2; ++i) {
            const int r = srow + 64 * i;
            GLOAD_LDS16(X + (size_t)(by * 128 + r) * EE + k0 + scol, &sm.st.A[r][scol]);
            GLOAD_LDS16(W + (size_t)(bx * 128 + r) * EE + k0 + scol, &sm.st.B[r][scol]);
        }
        __builtin_amdgcn_s_waitcnt(0);
        __syncthreads();
        bf16x8 af[4], bfr[4];
#pragma unroll
        for (int im = 0; im < 4; ++im)
            af[im] = *(const bf16x8*)&sm.st.A[wm * 64 + im * 16 + lr][kg * 8];
#pragma unroll
        for (int in = 0; in < 4; ++in)
            bfr[in] = *(const bf16x8*)&sm.st.B[wn * 64 + in * 16 + lr][kg * 8];
#pragma unroll
        for (int im = 0; im < 4; ++im)
#pragma unroll
            for (int in = 0; in < 4; ++in)
                acc[im][in] = mfma16(af[im], bfr[in], acc[im][in]);
        __syncthreads();
    }

    // C/D layout (16x16x32): col = lane&15, row = (lane>>4)*4 + reg  [m89]
    // acc -> LDS (bias added), then coalesced 16B-per-lane stores.
#pragma unroll
    for (int im = 0; im < 4; ++im) {
        const int row = wm * 64 + im * 16 + kg * 4;
#pragma unroll
        for (int in = 0; in < 4; ++in) {
            const int col = wn * 64 + in * 16 + lr;
            const float bias = Bv[bx * 128 + col];
#pragma unroll
            for (int r = 0; r < 4; ++r)
                sm.ep[row + r][col] = (bf16)(acc[im][in][r] + bias);
        }
    }
    __syncthreads();
#pragma unroll
    for (int i = 0; i < 8; ++i) {
        const int c = i * 256 + t;
        const int row = c >> 4, colg = (c & 15) * 8;
        *(uint4*)(O + (size_t)(by * 128 + row) * EE + bx * 128 + colg) =
            *(const uint4*)&sm.ep[row][colg];
    }
}

// ---------------------------------------------------------------------------
// Scores: S[m][n] = f16( (Q[m][n] @ K[m][n]^T) * inv_scale ), all 4 maps x 8
// batches in one launch. grid (8, 8, 32): x = col tile, y = row tile,
// z = map*8 + batch. LDS-repack epilogue.
// ---------------------------------------------------------------------------
struct ScoresParams {
    const bf16* q[4];
    const bf16* k[4];
    f16* s[4];
};

__global__ __launch_bounds__(256) void scores_kernel(ScoresParams p) {
    const int map = blockIdx.z >> 3;
    const int n = blockIdx.z & 7;
    const bf16* __restrict__ Qb = p.q[map] + (size_t)n * LL * EE;
    const bf16* __restrict__ Kb = p.k[map] + (size_t)n * LL * EE;
    f16* __restrict__ Sb = p.s[map] + (size_t)n * LL * LL;

    __shared__ union {
        struct { alignas(16) bf16 A[128][32]; alignas(16) bf16 B[128][32]; } st;
        alignas(16) f16 ep[128][140];
    } sm;

    const int t = threadIdx.x;
    const int lane = t & 63, wid = t >> 6;
    const int wm = wid & 1, wn = wid >> 1;
    const int lr = lane & 15, kg = lane >> 4;
    const int bx = blockIdx.x, by = blockIdx.y;

    f32x4 acc[4][4] = {};

    const int srow = t >> 2;
    const int scol = (t & 3) * 8;

    for (int k0 = 0; k0 < EE; k0 += 32) {
#pragma unroll
        for (int i = 0; i < 2; ++i) {
            const int r = srow + 64 * i;
            GLOAD_LDS16(Qb + (size_t)(by * 128 + r) * EE + k0 + scol, &sm.st.A[r][scol]);
            GLOAD_LDS16(Kb + (size_t)(bx * 128 + r) * EE + k0 + scol, &sm.st.B[r][scol]);
        }
        __builtin_amdgcn_s_waitcnt(0);
        __syncthreads();
        bf16x8 af[4], bfr[4];
#pragma unroll
        for (int im = 0; im < 4; ++im)
            af[im] = *(const bf16x8*)&sm.st.A[wm * 64 + im * 16 + lr][kg * 8];
#pragma unroll
        for (int in = 0; in < 4; ++in)
            bfr[in] = *(const bf16x8*)&sm.st.B[wn * 64 + in * 16 + lr][kg * 8];
#pragma unroll
        for (int im = 0; im < 4; ++im)
#pragma unroll
            for (int in = 0; in < 4; ++in)
                acc[im][in] = mfma16(af[im], bfr[in], acc[im][in]);
        __syncthreads();
    }

    const float inv_scale = 0.011048543456039806f;  // 1/(4*sqrt(512))
#pragma unroll
    for (int im = 0; im < 4; ++im) {
        const int row = wm * 64 + im * 16 + kg * 4;
#pragma unroll
        for (int in = 0; in < 4; ++in) {
            const int col = wn * 64 + in * 16 + lr;
#pragma unroll
            for (int r = 0; r < 4; ++r)
                sm.ep[row + r][col] = (f16)(acc[im][in][r] * inv_scale);
        }
    }
    __syncthreads();
#pragma unroll
    for (int i = 0; i < 8; ++i) {
        const int c = i * 256 + t;
        const int row = c >> 4, colg = (c & 15) * 8;
        *(uint4*)(Sb + (size_t)(by * 128 + row) * LL + bx * 128 + colg) =
            *(const uint4*)&sm.ep[row][colg];
    }
}

// ---------------------------------------------------------------------------
// Row softmax (1024 cols, f16 in) over 8 batches, mean, write one quadrant.
// No max-subtraction: |S| small (sigma ~0.25), exp is exact-safe in fp32.
// grid (1024, 4): x = q row, y = map.
// ---------------------------------------------------------------------------
struct SmParams {
    const f16* s[4];
};

__global__ __launch_bounds__(256) void softmax_mean_kernel(SmParams p, float* __restrict__ out) {
    const int q = blockIdx.x;
    const int map = blockIdx.y;
    const f16* __restrict__ S = p.s[map];
    const int t = threadIdx.x;
    const int lane = t & 63, wid = t >> 6;
    __shared__ float red[NBATCH][4];

    f16x4 v[NBATCH];
#pragma unroll
    for (int n = 0; n < NBATCH; ++n)
        v[n] = *(const f16x4*)(S + ((size_t)n * LL + q) * LL + t * 4);

    float e[NBATCH][4];
#pragma unroll
    for (int n = 0; n < NBATCH; ++n) {
        float s = 0.f;
#pragma unroll
        for (int j = 0; j < 4; ++j) {
            e[n][j] = __expf((float)v[n][j]);
            s += e[n][j];
        }
#pragma unroll
        for (int off = 32; off; off >>= 1) s += __shfl_xor(s, off);
        if (lane == 0) red[n][wid] = s;
    }
    __syncthreads();

    float acc[4] = {};
#pragma unroll
    for (int n = 0; n < NBATCH; ++n) {
        const float inv = 1.0f / (red[n][0] + red[n][1] + red[n][2] + red[n][3]);
#pragma unroll
        for (int j = 0; j < 4; ++j) acc[j] += e[n][j] * inv;
    }

    const int orow = (map >= 2 ? LL : 0) + q;
    const int ocol = (map & 1 ? LL : 0) + t * 4;
    float4 o = make_float4(acc[0] * 0.125f, acc[1] * 0.125f, acc[2] * 0.125f, acc[3] * 0.125f);
    *(float4*)(out + (size_t)orow * (2 * LL) + ocol) = o;
}

// ---------------------------------------------------------------------------
extern "C" void kernel_launch(void* const* d_in, const int* in_sizes, int n_in,
                              void* d_out, int out_size, void* d_ws, size_t ws_size,
                              hipStream_t stream) {
    const float* modalA = (const float*)d_in[0];
    const float* modalB = (const float*)d_in[1];
    const float* WqA = (const float*)d_in[2];
    const float* bqA = (const float*)d_in[3];
    const float* WkA = (const float*)d_in[4];
    const float* bkA = (const float*)d_in[5];
    const float* WqB = (const float*)d_in[6];
    const float* bqB = (const float*)d_in[7];
    const float* WkB = (const float*)d_in[8];
    const float* bkB = (const float*)d_in[9];
    float* out = (float*)d_out;

    // ws layout (~100.7 MB of the 268 MB ws):
    //   [qk: 4 x 8192x512 bf16 = 33.55 MB]
    //   [region2: XA/XB/W4 bf16 (18.9 MB) then reused by S[4] f16 (67.1 MB)]
    // XA/XB/W4 are dead after proj_kernel; S written after. Stream-ordered.
    const size_t projN = (size_t)(NBATCH * LL) * EE;       // 4 Mi elems
    const size_t mapN = (size_t)NBATCH * LL * LL;          // 8 Mi elems per map
    char* base = (char*)d_ws;
    bf16* qk = (bf16*)base;
    char* region2 = base + 4 * projN * sizeof(bf16);
    bf16* XA = (bf16*)region2;
    bf16* XB = XA + projN;
    bf16* W4 = XB + projN;                                  // 4 x 512x512
    f16* S = (f16*)region2;

    CvtParams cp;
    cp.src[0] = modalA; cp.dst[0] = XA; cp.n4[0] = (int)(projN / 4);
    cp.src[1] = modalB; cp.dst[1] = XB; cp.n4[1] = (int)(projN / 4);
    const float* wsrc[4] = {WqA, WkA, WqB, WkB};
    for (int i = 0; i < 4; ++i) {
        cp.src[2 + i] = wsrc[i];
        cp.dst[2 + i] = W4 + (size_t)i * EE * EE;
        cp.n4[2 + i] = EE * EE / 4;
    }
    cvt_kernel<<<dim3(512, 6), 256, 0, stream>>>(cp);

    ProjParams pp;
    pp.x[0] = XA; pp.x[1] = XA; pp.x[2] = XB; pp.x[3] = XB;
    for (int i = 0; i < 4; ++i) pp.w[i] = W4 + (size_t)i * EE * EE;
    pp.b[0] = bqA; pp.b[1] = bkA; pp.b[2] = bqB; pp.b[3] = bkB;
    proj_kernel<<<dim3(4, 64, 4), 256, 0, stream>>>(pp, qk);

    const bf16* qA = qk + 0 * projN;
    const bf16* kA = qk + 1 * projN;
    const bf16* qB = qk + 2 * projN;
    const bf16* kB = qk + 3 * projN;

    // map order: 0=(qA,kA)->TL, 1=(qA,kB)->TR, 2=(qB,kB)->BL, 3=(qB,kA)->BR
    ScoresParams sp;
    sp.q[0] = qA; sp.q[1] = qA; sp.q[2] = qB; sp.q[3] = qB;
    sp.k[0] = kA; sp.k[1] = kB; sp.k[2] = kB; sp.k[3] = kA;
    for (int m = 0; m < 4; ++m) sp.s[m] = S + (size_t)m * mapN;
    scores_kernel<<<dim3(8, 8, 32), 256, 0, stream>>>(sp);

    SmParams smp;
    for (int m = 0; m < 4; ++m) smp.s[m] = S + (size_t)m * mapN;
    softmax_mean_kernel<<<dim3(1024, 4), 256, 0, stream>>>(smp, out);
}

// Round 4
// 194.887 us; speedup vs baseline: 1.3156x; 1.0405x over previous
//
#include <hip/hip_runtime.h>
#include <hip/hip_bf16.h>

typedef __bf16 bf16;
typedef bf16 bf16x8 __attribute__((ext_vector_type(8)));
typedef bf16 bf16x4v __attribute__((ext_vector_type(4)));
typedef _Float16 f16;
typedef f16 f16x4 __attribute__((ext_vector_type(4)));
typedef float f32x4 __attribute__((ext_vector_type(4)));

constexpr int LL = 1024;   // sequence length
constexpr int EE = 512;    // embed dim
constexpr int NBATCH = 8;

__device__ __forceinline__ f32x4 mfma16(bf16x8 a, bf16x8 b, f32x4 c) {
    return __builtin_amdgcn_mfma_f32_16x16x32_bf16(a, b, c, 0, 0, 0);
}

// global -> LDS direct DMA, 16B per lane; LDS dest = wave-uniform base + lane*16.
#define GLOAD_LDS16(g, l)                                                     \
    __builtin_amdgcn_global_load_lds(                                         \
        (const __attribute__((address_space(1))) void*)(g),                   \
        (__attribute__((address_space(3))) void*)(l), 16, 0, 0)

// ---------------------------------------------------------------------------
// fp32 -> bf16 conversion for modalA, modalB, and the 4 weight matrices.
// ---------------------------------------------------------------------------
struct CvtParams {
    const float* src[6];
    bf16* dst[6];
    int n4[6];  // element count / 4
};

__global__ __launch_bounds__(256) void cvt_kernel(CvtParams p) {
    const int y = blockIdx.y;
    const float* __restrict__ src = p.src[y];
    bf16* __restrict__ dst = p.dst[y];
    const int n4 = p.n4[y];
    for (int i = blockIdx.x * 256 + threadIdx.x; i < n4; i += gridDim.x * 256) {
        float4 v = *(const float4*)(src + (size_t)i * 4);
        bf16x4v o;
        o[0] = (bf16)v.x; o[1] = (bf16)v.y; o[2] = (bf16)v.z; o[3] = (bf16)v.w;
        *(bf16x4v*)(dst + (size_t)i * 4) = o;
    }
}

// ---------------------------------------------------------------------------
// Shared GEMM tile machinery.
// Staging layout is XOR-swizzled: LDS[row][cg] = G[row][cg ^ ((row>>1)&3)]
// (cg = 16B col-group). global_load_lds writes LDS lane-linearly, so we
// permute the GLOBAL source address per lane instead of the LDS dest.
// Fragment reads then hit bank quads (4*lr + kg^((lr>>1)&3))%8 -> each quad
// exactly 2x per 16-lane group = conflict-free (2-way is free, m136).
// ---------------------------------------------------------------------------

// ---------------------------------------------------------------------------
// Projection: O[z] = bf16( X[z] @ W[z]^T + b[z] ), bf16 NT GEMM, 128x128 tile,
// BK=32, m97 staging + swizzle, two-pass LDS-repack epilogue (17.4 KB union).
// grid (4, 64, 4): x = N tile, y = M tile, z = which projection.
// ---------------------------------------------------------------------------
struct ProjParams {
    const bf16* x[4];
    const bf16* w[4];
    const float* b[4];
};

__global__ __launch_bounds__(256) void proj_kernel(ProjParams p, bf16* __restrict__ outbase) {
    const int z = blockIdx.z;
    const bf16* __restrict__ X = p.x[z];
    const bf16* __restrict__ W = p.w[z];
    const float* __restrict__ Bv = p.b[z];
    bf16* __restrict__ O = outbase + (size_t)z * (NBATCH * LL) * EE;

    __shared__ union {
        struct { alignas(16) bf16 A[128][32]; alignas(16) bf16 B[128][32]; } st;
        alignas(16) bf16 ep[64][136];  // stride 136 (68 words ≡ 4 mod 32): balanced
    } sm;

    const int t = threadIdx.x;
    const int lane = t & 63, wid = t >> 6;
    const int wm = wid & 1, wn = wid >> 1;
    const int lr = lane & 15, kg = lane >> 4;
    const int bx = blockIdx.x, by = blockIdx.y;

    f32x4 acc[4][4] = {};

    const int srow = t >> 2;                        // 0..63
    const int cgl = t & 3;                          // LDS slot col-group
    const int gcg = (cgl ^ ((srow >> 1) & 3)) * 8;  // swizzled global col-group
    const int scg = (kg ^ ((lr >> 1) & 3)) * 8;     // swizzled LDS read col-group

    for (int k0 = 0; k0 < EE; k0 += 32) {
#pragma unroll
        for (int i = 0; i < 2; ++i) {
            const int r = srow + 64 * i;
            GLOAD_LDS16(X + (size_t)(by * 128 + r) * EE + k0 + gcg, &sm.st.A[r][cgl * 8]);
            GLOAD_LDS16(W + (size_t)(bx * 128 + r) * EE + k0 + gcg, &sm.st.B[r][cgl * 8]);
        }
        __builtin_amdgcn_s_waitcnt(0);
        __syncthreads();
        bf16x8 af[4], bfr[4];
#pragma unroll
        for (int im = 0; im < 4; ++im)
            af[im] = *(const bf16x8*)&sm.st.A[wm * 64 + im * 16 + lr][scg];
#pragma unroll
        for (int in = 0; in < 4; ++in)
            bfr[in] = *(const bf16x8*)&sm.st.B[wn * 64 + in * 16 + lr][scg];
#pragma unroll
        for (int im = 0; im < 4; ++im)
#pragma unroll
            for (int in = 0; in < 4; ++in)
                acc[im][in] = mfma16(af[im], bfr[in], acc[im][in]);
        __syncthreads();
    }

    // C/D layout (16x16x32): col = lane&15, row = (lane>>4)*4 + reg  [m89]
    // Two passes of 64 rows through the small repack buffer.
#pragma unroll
    for (int pph = 0; pph < 2; ++pph) {
        if (wm == pph) {
#pragma unroll
            for (int im = 0; im < 4; ++im) {
                const int row = im * 16 + kg * 4;
#pragma unroll
                for (int in = 0; in < 4; ++in) {
                    const int col = wn * 64 + in * 16 + lr;
                    const float bias = Bv[bx * 128 + col];
#pragma unroll
                    for (int r = 0; r < 4; ++r)
                        sm.ep[row + r][col] = (bf16)(acc[im][in][r] + bias);
                }
            }
        }
        __syncthreads();
#pragma unroll
        for (int i = 0; i < 4; ++i) {
            const int c = i * 256 + t;
            const int row = c >> 4, colg = (c & 15) * 8;
            *(uint4*)(O + (size_t)(by * 128 + pph * 64 + row) * EE + bx * 128 + colg) =
                *(const uint4*)&sm.ep[row][colg];
        }
        __syncthreads();
    }
}

// ---------------------------------------------------------------------------
// Scores: S[m][n] = f16( (Q[m][n] @ K[m][n]^T) * inv_scale ), all 4 maps x 8
// batches in one launch. XCD-aware swizzle: flat%8 (~XCD) owns 4 whole
// (map,batch) slices -> 2 MB Q+K working set per slice fits 4 MB per-XCD L2.
// ---------------------------------------------------------------------------
struct ScoresParams {
    const bf16* q[4];
    const bf16* k[4];
    f16* s[4];
};

__global__ __launch_bounds__(256) void scores_kernel(ScoresParams p) {
    const int f = blockIdx.x + (blockIdx.y << 3) + (blockIdx.z << 6);
    const int xcd = f & 7;
    const int j = f >> 3;            // 0..255 per XCD
    const int z = (xcd << 2) + (j >> 6);
    const int map = z >> 3, n = z & 7;
    const int tile = j & 63;
    const int bx = tile & 7, by = tile >> 3;

    const bf16* __restrict__ Qb = p.q[map] + (size_t)n * LL * EE;
    const bf16* __restrict__ Kb = p.k[map] + (size_t)n * LL * EE;
    f16* __restrict__ Sb = p.s[map] + (size_t)n * LL * LL;

    __shared__ union {
        struct { alignas(16) bf16 A[128][32]; alignas(16) bf16 B[128][32]; } st;
        alignas(16) f16 ep[64][136];
    } sm;

    const int t = threadIdx.x;
    const int lane = t & 63, wid = t >> 6;
    const int wm = wid & 1, wn = wid >> 1;
    const int lr = lane & 15, kg = lane >> 4;

    f32x4 acc[4][4] = {};

    const int srow = t >> 2;
    const int cgl = t & 3;
    const int gcg = (cgl ^ ((srow >> 1) & 3)) * 8;
    const int scg = (kg ^ ((lr >> 1) & 3)) * 8;

    for (int k0 = 0; k0 < EE; k0 += 32) {
#pragma unroll
        for (int i = 0; i < 2; ++i) {
            const int r = srow + 64 * i;
            GLOAD_LDS16(Qb + (size_t)(by * 128 + r) * EE + k0 + gcg, &sm.st.A[r][cgl * 8]);
            GLOAD_LDS16(Kb + (size_t)(bx * 128 + r) * EE + k0 + gcg, &sm.st.B[r][cgl * 8]);
        }
        __builtin_amdgcn_s_waitcnt(0);
        __syncthreads();
        bf16x8 af[4], bfr[4];
#pragma unroll
        for (int im = 0; im < 4; ++im)
            af[im] = *(const bf16x8*)&sm.st.A[wm * 64 + im * 16 + lr][scg];
#pragma unroll
        for (int in = 0; in < 4; ++in)
            bfr[in] = *(const bf16x8*)&sm.st.B[wn * 64 + in * 16 + lr][scg];
#pragma unroll
        for (int im = 0; im < 4; ++im)
#pragma unroll
            for (int in = 0; in < 4; ++in)
                acc[im][in] = mfma16(af[im], bfr[in], acc[im][in]);
        __syncthreads();
    }

    const float inv_scale = 0.011048543456039806f;  // 1/(4*sqrt(512))
#pragma unroll
    for (int pph = 0; pph < 2; ++pph) {
        if (wm == pph) {
#pragma unroll
            for (int im = 0; im < 4; ++im) {
                const int row = im * 16 + kg * 4;
#pragma unroll
                for (int in = 0; in < 4; ++in) {
                    const int col = wn * 64 + in * 16 + lr;
#pragma unroll
                    for (int r = 0; r < 4; ++r)
                        sm.ep[row + r][col] = (f16)(acc[im][in][r] * inv_scale);
                }
            }
        }
        __syncthreads();
#pragma unroll
        for (int i = 0; i < 4; ++i) {
            const int c = i * 256 + t;
            const int row = c >> 4, colg = (c & 15) * 8;
            *(uint4*)(Sb + (size_t)(by * 128 + pph * 64 + row) * LL + bx * 128 + colg) =
                *(const uint4*)&sm.ep[row][colg];
        }
        __syncthreads();
    }
}

// ---------------------------------------------------------------------------
// Row softmax (1024 cols, f16 in) over 8 batches, mean, write one quadrant.
// No max-subtraction: |S| small (sigma ~0.25), exp is exact-safe in fp32.
// grid (1024, 4): x = q row, y = map.
// ---------------------------------------------------------------------------
struct SmParams {
    const f16* s[4];
};

__global__ __launch_bounds__(256) void softmax_mean_kernel(SmParams p, float* __restrict__ out) {
    const int q = blockIdx.x;
    const int map = blockIdx.y;
    const f16* __restrict__ S = p.s[map];
    const int t = threadIdx.x;
    const int lane = t & 63, wid = t >> 6;
    __shared__ float red[NBATCH][4];

    f16x4 v[NBATCH];
#pragma unroll
    for (int n = 0; n < NBATCH; ++n)
        v[n] = *(const f16x4*)(S + ((size_t)n * LL + q) * LL + t * 4);

    float e[NBATCH][4];
#pragma unroll
    for (int n = 0; n < NBATCH; ++n) {
        float s = 0.f;
#pragma unroll
        for (int j = 0; j < 4; ++j) {
            e[n][j] = __expf((float)v[n][j]);
            s += e[n][j];
        }
#pragma unroll
        for (int off = 32; off; off >>= 1) s += __shfl_xor(s, off);
        if (lane == 0) red[n][wid] = s;
    }
    __syncthreads();

    float acc[4] = {};
#pragma unroll
    for (int n = 0; n < NBATCH; ++n) {
        const float inv = 1.0f / (red[n][0] + red[n][1] + red[n][2] + red[n][3]);
#pragma unroll
        for (int j = 0; j < 4; ++j) acc[j] += e[n][j] * inv;
    }

    const int orow = (map >= 2 ? LL : 0) + q;
    const int ocol = (map & 1 ? LL : 0) + t * 4;
    float4 o = make_float4(acc[0] * 0.125f, acc[1] * 0.125f, acc[2] * 0.125f, acc[3] * 0.125f);
    *(float4*)(out + (size_t)orow * (2 * LL) + ocol) = o;
}

// ---------------------------------------------------------------------------
extern "C" void kernel_launch(void* const* d_in, const int* in_sizes, int n_in,
                              void* d_out, int out_size, void* d_ws, size_t ws_size,
                              hipStream_t stream) {
    const float* modalA = (const float*)d_in[0];
    const float* modalB = (const float*)d_in[1];
    const float* WqA = (const float*)d_in[2];
    const float* bqA = (const float*)d_in[3];
    const float* WkA = (const float*)d_in[4];
    const float* bkA = (const float*)d_in[5];
    const float* WqB = (const float*)d_in[6];
    const float* bqB = (const float*)d_in[7];
    const float* WkB = (const float*)d_in[8];
    const float* bkB = (const float*)d_in[9];
    float* out = (float*)d_out;

    // ws layout (~100.7 MB):
    //   [qk: 4 x 8192x512 bf16 = 33.55 MB]
    //   [region2: XA/XB/W4 bf16 (18.9 MB) then reused by S[4] f16 (67.1 MB)]
    const size_t projN = (size_t)(NBATCH * LL) * EE;       // 4 Mi elems
    const size_t mapN = (size_t)NBATCH * LL * LL;          // 8 Mi elems per map
    char* base = (char*)d_ws;
    bf16* qk = (bf16*)base;
    char* region2 = base + 4 * projN * sizeof(bf16);
    bf16* XA = (bf16*)region2;
    bf16* XB = XA + projN;
    bf16* W4 = XB + projN;                                  // 4 x 512x512
    f16* S = (f16*)region2;

    CvtParams cp;
    cp.src[0] = modalA; cp.dst[0] = XA; cp.n4[0] = (int)(projN / 4);
    cp.src[1] = modalB; cp.dst[1] = XB; cp.n4[1] = (int)(projN / 4);
    const float* wsrc[4] = {WqA, WkA, WqB, WkB};
    for (int i = 0; i < 4; ++i) {
        cp.src[2 + i] = wsrc[i];
        cp.dst[2 + i] = W4 + (size_t)i * EE * EE;
        cp.n4[2 + i] = EE * EE / 4;
    }
    cvt_kernel<<<dim3(512, 6), 256, 0, stream>>>(cp);

    ProjParams pp;
    pp.x[0] = XA; pp.x[1] = XA; pp.x[2] = XB; pp.x[3] = XB;
    for (int i = 0; i < 4; ++i) pp.w[i] = W4 + (size_t)i * EE * EE;
    pp.b[0] = bqA; pp.b[1] = bkA; pp.b[2] = bqB; pp.b[3] = bkB;
    proj_kernel<<<dim3(4, 64, 4), 256, 0, stream>>>(pp, qk);

    const bf16* qA = qk + 0 * projN;
    const bf16* kA = qk + 1 * projN;
    const bf16* qB = qk + 2 * projN;
    const bf16* kB = qk + 3 * projN;

    // map order: 0=(qA,kA)->TL, 1=(qA,kB)->TR, 2=(qB,kB)->BL, 3=(qB,kA)->BR
    ScoresParams sp;
    sp.q[0] = qA; sp.q[1] = qA; sp.q[2] = qB; sp.q[3] = qB;
    sp.k[0] = kA; sp.k[1] = kB; sp.k[2] = kB; sp.k[3] = kA;
    for (int m = 0; m < 4; ++m) sp.s[m] = S + (size_t)m * mapN;
    scores_kernel<<<dim3(8, 8, 32), 256, 0, stream>>>(sp);

    SmParams smp;
    for (int m = 0; m < 4; ++m) smp.s[m] = S + (size_t)m * mapN;
    softmax_mean_kernel<<<dim3(1024, 4), 256, 0, stream>>>(smp, out);
}

// Round 5
// 189.067 us; speedup vs baseline: 1.3561x; 1.0308x over previous
//
#include <hip/hip_runtime.h>
#include <hip/hip_bf16.h>

typedef __bf16 bf16;
typedef bf16 bf16x8 __attribute__((ext_vector_type(8)));
typedef bf16 bf16x4v __attribute__((ext_vector_type(4)));
typedef _Float16 f16;
typedef f16 f16x4 __attribute__((ext_vector_type(4)));
typedef float f32x4 __attribute__((ext_vector_type(4)));

constexpr int LL = 1024;   // sequence length
constexpr int EE = 512;    // embed dim
constexpr int NBATCH = 8;

__device__ __forceinline__ f32x4 mfma16(bf16x8 a, bf16x8 b, f32x4 c) {
    return __builtin_amdgcn_mfma_f32_16x16x32_bf16(a, b, c, 0, 0, 0);
}

// global -> LDS direct DMA, 16B per lane; LDS dest = wave-uniform base + lane*16.
#define GLOAD_LDS16(g, l)                                                     \
    __builtin_amdgcn_global_load_lds(                                         \
        (const __attribute__((address_space(1))) void*)(g),                   \
        (__attribute__((address_space(3))) void*)(l), 16, 0, 0)

// ---------------------------------------------------------------------------
// fp32 -> bf16 conversion for modalA, modalB, and the 4 weight matrices.
// ---------------------------------------------------------------------------
struct CvtParams {
    const float* src[6];
    bf16* dst[6];
    int n4[6];  // element count / 4
};

__global__ __launch_bounds__(256) void cvt_kernel(CvtParams p) {
    const int y = blockIdx.y;
    const float* __restrict__ src = p.src[y];
    bf16* __restrict__ dst = p.dst[y];
    const int n4 = p.n4[y];
    for (int i = blockIdx.x * 256 + threadIdx.x; i < n4; i += gridDim.x * 256) {
        float4 v = *(const float4*)(src + (size_t)i * 4);
        bf16x4v o;
        o[0] = (bf16)v.x; o[1] = (bf16)v.y; o[2] = (bf16)v.z; o[3] = (bf16)v.w;
        *(bf16x4v*)(dst + (size_t)i * 4) = o;
    }
}

// ---------------------------------------------------------------------------
// GEMM tile machinery (shared by proj and scores):
//  - XOR-swizzled staging: LDS[row][cg] = G[row][cg ^ ((row>>1)&3)]; fragment
//    reads hit each bank-quad exactly 2x per 16-lane group = conflict-free.
//  - Ping-pong double-buffered K-loop, ONE barrier per iter: issue loads(k+1)
//    after the barrier, compute(k) from the other buffer; compiler's
//    vmcnt(0)-before-barrier then hides the ~200cyc L2 latency behind compute.
//  - Two-pass LDS-repack epilogue for coalesced 16B stores.
// ---------------------------------------------------------------------------

// ---------------------------------------------------------------------------
// Projection: O[z] = bf16( X[z] @ W[z]^T + b[z] ), bf16 NT GEMM, 128x128 tile.
// grid (4, 64, 4): x = N tile, y = M tile, z = which projection.
// ---------------------------------------------------------------------------
struct ProjParams {
    const bf16* x[4];
    const bf16* w[4];
    const float* b[4];
};

__global__ __launch_bounds__(256) void proj_kernel(ProjParams p, bf16* __restrict__ outbase) {
    const int z = blockIdx.z;
    const bf16* __restrict__ X = p.x[z];
    const bf16* __restrict__ W = p.w[z];
    const float* __restrict__ Bv = p.b[z];
    bf16* __restrict__ O = outbase + (size_t)z * (NBATCH * LL) * EE;

    __shared__ union {
        struct { alignas(16) bf16 A[2][128][32]; alignas(16) bf16 B[2][128][32]; } st;
        alignas(16) bf16 ep[64][136];  // stride 136 (68 words ≡ 4 mod 32): balanced
    } sm;

    const int t = threadIdx.x;
    const int lane = t & 63, wid = t >> 6;
    const int wm = wid & 1, wn = wid >> 1;
    const int lr = lane & 15, kg = lane >> 4;
    const int bx = blockIdx.x, by = blockIdx.y;

    f32x4 acc[4][4] = {};

    const int srow = t >> 2;                        // 0..63
    const int cgl = t & 3;                          // LDS slot col-group
    const int gcg = (cgl ^ ((srow >> 1) & 3)) * 8;  // swizzled global col-group
    const int scg = (kg ^ ((lr >> 1) & 3)) * 8;     // swizzled LDS read col-group

    const bf16* Xrow0 = X + (size_t)(by * 128 + srow) * EE + gcg;
    const bf16* Wrow0 = W + (size_t)(bx * 128 + srow) * EE + gcg;

    auto stage = [&](int k, int b) {
        const int k0 = k * 32;
#pragma unroll
        for (int i = 0; i < 2; ++i) {
            GLOAD_LDS16(Xrow0 + (size_t)(64 * i) * EE + k0, &sm.st.A[b][srow + 64 * i][cgl * 8]);
            GLOAD_LDS16(Wrow0 + (size_t)(64 * i) * EE + k0, &sm.st.B[b][srow + 64 * i][cgl * 8]);
        }
    };
    auto compute = [&](int b) {
        bf16x8 af[4], bfr[4];
#pragma unroll
        for (int im = 0; im < 4; ++im)
            af[im] = *(const bf16x8*)&sm.st.A[b][wm * 64 + im * 16 + lr][scg];
#pragma unroll
        for (int in = 0; in < 4; ++in)
            bfr[in] = *(const bf16x8*)&sm.st.B[b][wn * 64 + in * 16 + lr][scg];
#pragma unroll
        for (int im = 0; im < 4; ++im)
#pragma unroll
            for (int in = 0; in < 4; ++in)
                acc[im][in] = mfma16(af[im], bfr[in], acc[im][in]);
    };

    stage(0, 0);
#pragma unroll
    for (int k = 0; k < 16; ++k) {
        __builtin_amdgcn_s_waitcnt(0);  // drain loads(k); loads(k+1) not yet issued
        __syncthreads();
        if (k < 15) stage(k + 1, (k + 1) & 1);
        compute(k & 1);
    }
    __syncthreads();

    // C/D layout (16x16x32): col = lane&15, row = (lane>>4)*4 + reg  [m89]
#pragma unroll
    for (int pph = 0; pph < 2; ++pph) {
        if (wm == pph) {
#pragma unroll
            for (int im = 0; im < 4; ++im) {
                const int row = im * 16 + kg * 4;
#pragma unroll
                for (int in = 0; in < 4; ++in) {
                    const int col = wn * 64 + in * 16 + lr;
                    const float bias = Bv[bx * 128 + col];
#pragma unroll
                    for (int r = 0; r < 4; ++r)
                        sm.ep[row + r][col] = (bf16)(acc[im][in][r] + bias);
                }
            }
        }
        __syncthreads();
#pragma unroll
        for (int i = 0; i < 4; ++i) {
            const int c = i * 256 + t;
            const int row = c >> 4, colg = (c & 15) * 8;
            *(uint4*)(O + (size_t)(by * 128 + pph * 64 + row) * EE + bx * 128 + colg) =
                *(const uint4*)&sm.ep[row][colg];
        }
        __syncthreads();
    }
}

// ---------------------------------------------------------------------------
// Scores: S[m][n] = f16( (Q[m][n] @ K[m][n]^T) * inv_scale ), all 4 maps x 8
// batches in one launch. XCD-aware swizzle: flat%8 (~XCD) owns 4 whole
// (map,batch) slices -> 2 MB Q+K working set per slice fits 4 MB per-XCD L2.
// ---------------------------------------------------------------------------
struct ScoresParams {
    const bf16* q[4];
    const bf16* k[4];
    f16* s[4];
};

__global__ __launch_bounds__(256) void scores_kernel(ScoresParams p) {
    const int f = blockIdx.x + (blockIdx.y << 3) + (blockIdx.z << 6);
    const int xcd = f & 7;
    const int j = f >> 3;            // 0..255 per XCD
    const int z = (xcd << 2) + (j >> 6);
    const int map = z >> 3, n = z & 7;
    const int tile = j & 63;
    const int bx = tile & 7, by = tile >> 3;

    const bf16* __restrict__ Qb = p.q[map] + (size_t)n * LL * EE;
    const bf16* __restrict__ Kb = p.k[map] + (size_t)n * LL * EE;
    f16* __restrict__ Sb = p.s[map] + (size_t)n * LL * LL;

    __shared__ union {
        struct { alignas(16) bf16 A[2][128][32]; alignas(16) bf16 B[2][128][32]; } st;
        alignas(16) f16 ep[64][136];
    } sm;

    const int t = threadIdx.x;
    const int lane = t & 63, wid = t >> 6;
    const int wm = wid & 1, wn = wid >> 1;
    const int lr = lane & 15, kg = lane >> 4;

    f32x4 acc[4][4] = {};

    const int srow = t >> 2;
    const int cgl = t & 3;
    const int gcg = (cgl ^ ((srow >> 1) & 3)) * 8;
    const int scg = (kg ^ ((lr >> 1) & 3)) * 8;

    const bf16* Qrow0 = Qb + (size_t)(by * 128 + srow) * EE + gcg;
    const bf16* Krow0 = Kb + (size_t)(bx * 128 + srow) * EE + gcg;

    auto stage = [&](int k, int b) {
        const int k0 = k * 32;
#pragma unroll
        for (int i = 0; i < 2; ++i) {
            GLOAD_LDS16(Qrow0 + (size_t)(64 * i) * EE + k0, &sm.st.A[b][srow + 64 * i][cgl * 8]);
            GLOAD_LDS16(Krow0 + (size_t)(64 * i) * EE + k0, &sm.st.B[b][srow + 64 * i][cgl * 8]);
        }
    };
    auto compute = [&](int b) {
        bf16x8 af[4], bfr[4];
#pragma unroll
        for (int im = 0; im < 4; ++im)
            af[im] = *(const bf16x8*)&sm.st.A[b][wm * 64 + im * 16 + lr][scg];
#pragma unroll
        for (int in = 0; in < 4; ++in)
            bfr[in] = *(const bf16x8*)&sm.st.B[b][wn * 64 + in * 16 + lr][scg];
#pragma unroll
        for (int im = 0; im < 4; ++im)
#pragma unroll
            for (int in = 0; in < 4; ++in)
                acc[im][in] = mfma16(af[im], bfr[in], acc[im][in]);
    };

    stage(0, 0);
#pragma unroll
    for (int k = 0; k < 16; ++k) {
        __builtin_amdgcn_s_waitcnt(0);
        __syncthreads();
        if (k < 15) stage(k + 1, (k + 1) & 1);
        compute(k & 1);
    }
    __syncthreads();

    const float inv_scale = 0.011048543456039806f;  // 1/(4*sqrt(512))
#pragma unroll
    for (int pph = 0; pph < 2; ++pph) {
        if (wm == pph) {
#pragma unroll
            for (int im = 0; im < 4; ++im) {
                const int row = im * 16 + kg * 4;
#pragma unroll
                for (int in = 0; in < 4; ++in) {
                    const int col = wn * 64 + in * 16 + lr;
#pragma unroll
                    for (int r = 0; r < 4; ++r)
                        sm.ep[row + r][col] = (f16)(acc[im][in][r] * inv_scale);
                }
            }
        }
        __syncthreads();
#pragma unroll
        for (int i = 0; i < 4; ++i) {
            const int c = i * 256 + t;
            const int row = c >> 4, colg = (c & 15) * 8;
            *(uint4*)(Sb + (size_t)(by * 128 + pph * 64 + row) * LL + bx * 128 + colg) =
                *(const uint4*)&sm.ep[row][colg];
        }
        __syncthreads();
    }
}

// ---------------------------------------------------------------------------
// Row softmax (1024 cols, f16 in) over 8 batches, mean, write one quadrant.
// No max-subtraction: |S| small (sigma ~0.25), exp is exact-safe in fp32.
// grid (1024, 4): x = q row, y = map.
// ---------------------------------------------------------------------------
struct SmParams {
    const f16* s[4];
};

__global__ __launch_bounds__(256) void softmax_mean_kernel(SmParams p, float* __restrict__ out) {
    const int q = blockIdx.x;
    const int map = blockIdx.y;
    const f16* __restrict__ S = p.s[map];
    const int t = threadIdx.x;
    const int lane = t & 63, wid = t >> 6;
    __shared__ float red[NBATCH][4];

    f16x4 v[NBATCH];
#pragma unroll
    for (int n = 0; n < NBATCH; ++n)
        v[n] = *(const f16x4*)(S + ((size_t)n * LL + q) * LL + t * 4);

    float e[NBATCH][4];
#pragma unroll
    for (int n = 0; n < NBATCH; ++n) {
        float s = 0.f;
#pragma unroll
        for (int j = 0; j < 4; ++j) {
            e[n][j] = __expf((float)v[n][j]);
            s += e[n][j];
        }
#pragma unroll
        for (int off = 32; off; off >>= 1) s += __shfl_xor(s, off);
        if (lane == 0) red[n][wid] = s;
    }
    __syncthreads();

    float acc[4] = {};
#pragma unroll
    for (int n = 0; n < NBATCH; ++n) {
        const float inv = 1.0f / (red[n][0] + red[n][1] + red[n][2] + red[n][3]);
#pragma unroll
        for (int j = 0; j < 4; ++j) acc[j] += e[n][j] * inv;
    }

    const int orow = (map >= 2 ? LL : 0) + q;
    const int ocol = (map & 1 ? LL : 0) + t * 4;
    float4 o = make_float4(acc[0] * 0.125f, acc[1] * 0.125f, acc[2] * 0.125f, acc[3] * 0.125f);
    *(float4*)(out + (size_t)orow * (2 * LL) + ocol) = o;
}

// ---------------------------------------------------------------------------
extern "C" void kernel_launch(void* const* d_in, const int* in_sizes, int n_in,
                              void* d_out, int out_size, void* d_ws, size_t ws_size,
                              hipStream_t stream) {
    const float* modalA = (const float*)d_in[0];
    const float* modalB = (const float*)d_in[1];
    const float* WqA = (const float*)d_in[2];
    const float* bqA = (const float*)d_in[3];
    const float* WkA = (const float*)d_in[4];
    const float* bkA = (const float*)d_in[5];
    const float* WqB = (const float*)d_in[6];
    const float* bqB = (const float*)d_in[7];
    const float* WkB = (const float*)d_in[8];
    const float* bkB = (const float*)d_in[9];
    float* out = (float*)d_out;

    // ws layout (~100.7 MB):
    //   [qk: 4 x 8192x512 bf16 = 33.55 MB]
    //   [region2: XA/XB/W4 bf16 (18.9 MB) then reused by S[4] f16 (67.1 MB)]
    const size_t projN = (size_t)(NBATCH * LL) * EE;       // 4 Mi elems
    const size_t mapN = (size_t)NBATCH * LL * LL;          // 8 Mi elems per map
    char* base = (char*)d_ws;
    bf16* qk = (bf16*)base;
    char* region2 = base + 4 * projN * sizeof(bf16);
    bf16* XA = (bf16*)region2;
    bf16* XB = XA + projN;
    bf16* W4 = XB + projN;                                  // 4 x 512x512
    f16* S = (f16*)region2;

    CvtParams cp;
    cp.src[0] = modalA; cp.dst[0] = XA; cp.n4[0] = (int)(projN / 4);
    cp.src[1] = modalB; cp.dst[1] = XB; cp.n4[1] = (int)(projN / 4);
    const float* wsrc[4] = {WqA, WkA, WqB, WkB};
    for (int i = 0; i < 4; ++i) {
        cp.src[2 + i] = wsrc[i];
        cp.dst[2 + i] = W4 + (size_t)i * EE * EE;
        cp.n4[2 + i] = EE * EE / 4;
    }
    cvt_kernel<<<dim3(512, 6), 256, 0, stream>>>(cp);

    ProjParams pp;
    pp.x[0] = XA; pp.x[1] = XA; pp.x[2] = XB; pp.x[3] = XB;
    for (int i = 0; i < 4; ++i) pp.w[i] = W4 + (size_t)i * EE * EE;
    pp.b[0] = bqA; pp.b[1] = bkA; pp.b[2] = bqB; pp.b[3] = bkB;
    proj_kernel<<<dim3(4, 64, 4), 256, 0, stream>>>(pp, qk);

    const bf16* qA = qk + 0 * projN;
    const bf16* kA = qk + 1 * projN;
    const bf16* qB = qk + 2 * projN;
    const bf16* kB = qk + 3 * projN;

    // map order: 0=(qA,kA)->TL, 1=(qA,kB)->TR, 2=(qB,kB)->BL, 3=(qB,kA)->BR
    ScoresParams sp;
    sp.q[0] = qA; sp.q[1] = qA; sp.q[2] = qB; sp.q[3] = qB;
    sp.k[0] = kA; sp.k[1] = kB; sp.k[2] = kB; sp.k[3] = kA;
    for (int m = 0; m < 4; ++m) sp.s[m] = S + (size_t)m * mapN;
    scores_kernel<<<dim3(8, 8, 32), 256, 0, stream>>>(sp);

    SmParams smp;
    for (int m = 0; m < 4; ++m) smp.s[m] = S + (size_t)m * mapN;
    softmax_mean_kernel<<<dim3(1024, 4), 256, 0, stream>>>(smp, out);
}

// Round 6
// 180.266 us; speedup vs baseline: 1.4223x; 1.0488x over previous
//
#include <hip/hip_runtime.h>
#include <hip/hip_bf16.h>

typedef __bf16 bf16;
typedef bf16 bf16x8 __attribute__((ext_vector_type(8)));
typedef bf16 bf16x4v __attribute__((ext_vector_type(4)));
typedef _Float16 f16;
typedef f16 f16x4 __attribute__((ext_vector_type(4)));
typedef float f32x4 __attribute__((ext_vector_type(4)));

constexpr int LL = 1024;   // sequence length
constexpr int EE = 512;    // embed dim
constexpr int NBATCH = 8;

__device__ __forceinline__ f32x4 mfma16(bf16x8 a, bf16x8 b, f32x4 c) {
    return __builtin_amdgcn_mfma_f32_16x16x32_bf16(a, b, c, 0, 0, 0);
}

// global -> LDS direct DMA, 16B per lane; LDS dest = wave-uniform base + lane*16.
#define GLOAD_LDS16(g, l)                                                     \
    __builtin_amdgcn_global_load_lds(                                         \
        (const __attribute__((address_space(1))) void*)(g),                   \
        (__attribute__((address_space(3))) void*)(l), 16, 0, 0)

// ---------------------------------------------------------------------------
// fp32 -> bf16 conversion for modalA, modalB, and the 4 weight matrices.
// ---------------------------------------------------------------------------
struct CvtParams {
    const float* src[6];
    bf16* dst[6];
    int n4[6];  // element count / 4
};

__global__ __launch_bounds__(256) void cvt_kernel(CvtParams p) {
    const int y = blockIdx.y;
    const float* __restrict__ src = p.src[y];
    bf16* __restrict__ dst = p.dst[y];
    const int n4 = p.n4[y];
    for (int i = blockIdx.x * 256 + threadIdx.x; i < n4; i += gridDim.x * 256) {
        float4 v = *(const float4*)(src + (size_t)i * 4);
        bf16x4v o;
        o[0] = (bf16)v.x; o[1] = (bf16)v.y; o[2] = (bf16)v.z; o[3] = (bf16)v.w;
        *(bf16x4v*)(dst + (size_t)i * 4) = o;
    }
}

// ---------------------------------------------------------------------------
// GEMM tile machinery: 128x256 output tile per block, 4 waves each owning
// 64x128 (4 A-frags + 8 B-frags -> 32 MFMAs from 12 KB LDS reads = 42.7
// FLOP/LDS-byte, vs 32 for the 64x64 layout). XOR-swizzled staging keeps
// fragment ds_read_b128 conflict-free. Ping-pong dbuf, one barrier/iter.
// acc = 128 AGPRs/wave; __launch_bounds__(256,2) caps regs for 2 blocks/CU.
// ---------------------------------------------------------------------------

// ---------------------------------------------------------------------------
// Projection: O[z] = bf16( X[z] @ W[z]^T + b[z] ), bf16 NT GEMM.
// grid flat 512: z = f>>7, j = f&127: bxp = j&1 (col 256-half), by = j>>1.
// ---------------------------------------------------------------------------
struct ProjParams {
    const bf16* x[4];
    const bf16* w[4];
    const float* b[4];
};

__global__ __launch_bounds__(256, 2) void proj_kernel(ProjParams p, bf16* __restrict__ outbase) {
    const int f = blockIdx.x;
    const int z = f >> 7;
    const int j = f & 127;
    const int bxp = j & 1, by = j >> 1;

    const bf16* __restrict__ X = p.x[z];
    const bf16* __restrict__ W = p.w[z];
    const float* __restrict__ Bv = p.b[z];
    bf16* __restrict__ O = outbase + (size_t)z * (NBATCH * LL) * EE;

    __shared__ union {
        struct { alignas(16) bf16 A[2][128][32]; alignas(16) bf16 B[2][256][32]; } st;
        alignas(16) bf16 ep[64][264];  // stride 264 (132 words ≡ 4 mod 32): balanced
    } sm;

    const int t = threadIdx.x;
    const int lane = t & 63, wid = t >> 6;
    const int wm = wid & 1, wn = wid >> 1;   // wave: rows 64*wm.., cols 128*wn..
    const int lr = lane & 15, kg = lane >> 4;

    f32x4 acc[4][8] = {};

    const int srow = t >> 2;                        // 0..63
    const int cgl = t & 3;                          // LDS slot col-group
    const int gcg = (cgl ^ ((srow >> 1) & 3)) * 8;  // swizzled global col-group
    const int scg = (kg ^ ((lr >> 1) & 3)) * 8;     // swizzled LDS read col-group

    const bf16* Xrow0 = X + (size_t)(by * 128 + srow) * EE + gcg;
    const bf16* Wrow0 = W + (size_t)(bxp * 256 + srow) * EE + gcg;

    auto stage = [&](int k, int b) {
        const int k0 = k * 32;
#pragma unroll
        for (int i = 0; i < 2; ++i)
            GLOAD_LDS16(Xrow0 + (size_t)(64 * i) * EE + k0, &sm.st.A[b][srow + 64 * i][cgl * 8]);
#pragma unroll
        for (int i = 0; i < 4; ++i)
            GLOAD_LDS16(Wrow0 + (size_t)(64 * i) * EE + k0, &sm.st.B[b][srow + 64 * i][cgl * 8]);
    };
    auto compute = [&](int b) {
        bf16x8 af[4], bfr[8];
#pragma unroll
        for (int im = 0; im < 4; ++im)
            af[im] = *(const bf16x8*)&sm.st.A[b][wm * 64 + im * 16 + lr][scg];
#pragma unroll
        for (int in = 0; in < 8; ++in)
            bfr[in] = *(const bf16x8*)&sm.st.B[b][wn * 128 + in * 16 + lr][scg];
#pragma unroll
        for (int im = 0; im < 4; ++im)
#pragma unroll
            for (int in = 0; in < 8; ++in)
                acc[im][in] = mfma16(af[im], bfr[in], acc[im][in]);
    };

    stage(0, 0);
#pragma unroll
    for (int k = 0; k < 16; ++k) {
        __builtin_amdgcn_s_waitcnt(0);  // drain loads(k); hidden behind compute(k-1)
        __syncthreads();
        if (k < 15) stage(k + 1, (k + 1) & 1);
        compute(k & 1);
    }
    __syncthreads();

    // C/D layout (16x16x32): col = lane&15, row = (lane>>4)*4 + reg  [m89]
#pragma unroll
    for (int pph = 0; pph < 2; ++pph) {
        if (wm == pph) {
#pragma unroll
            for (int im = 0; im < 4; ++im) {
                const int row = im * 16 + kg * 4;
#pragma unroll
                for (int in = 0; in < 8; ++in) {
                    const int col = wn * 128 + in * 16 + lr;
                    const float bias = Bv[bxp * 256 + col];
#pragma unroll
                    for (int r = 0; r < 4; ++r)
                        sm.ep[row + r][col] = (bf16)(acc[im][in][r] + bias);
                }
            }
        }
        __syncthreads();
#pragma unroll
        for (int i = 0; i < 8; ++i) {
            const int c = i * 256 + t;              // 0..2047
            const int row = c >> 5, colg = (c & 31) * 8;
            *(uint4*)(O + (size_t)(by * 128 + pph * 64 + row) * EE + bxp * 256 + colg) =
                *(const uint4*)&sm.ep[row][colg];
        }
        __syncthreads();
    }
}

// ---------------------------------------------------------------------------
// Scores: S[m][n] = f16( (Q[m][n] @ K[m][n]^T) * inv_scale ). 128x256 tiles.
// grid flat 1024. XCD swizzle: f&7 (~XCD) owns 4 whole (map,batch) slices
// (32 tiles each) -> 2 MB Q+K per slice fits per-XCD L2.
// ---------------------------------------------------------------------------
struct ScoresParams {
    const bf16* q[4];
    const bf16* k[4];
    f16* s[4];
};

__global__ __launch_bounds__(256, 2) void scores_kernel(ScoresParams p) {
    const int f = blockIdx.x;
    const int xcd = f & 7;
    const int j = f >> 3;            // 0..127 per XCD
    const int z = (xcd << 2) + (j >> 5);
    const int map = z >> 3, n = z & 7;
    const int tile = j & 31;
    const int bxp = tile & 3, by = tile >> 2;

    const bf16* __restrict__ Qb = p.q[map] + (size_t)n * LL * EE;
    const bf16* __restrict__ Kb = p.k[map] + (size_t)n * LL * EE;
    f16* __restrict__ Sb = p.s[map] + (size_t)n * LL * LL;

    __shared__ union {
        struct { alignas(16) bf16 A[2][128][32]; alignas(16) bf16 B[2][256][32]; } st;
        alignas(16) f16 ep[64][264];
    } sm;

    const int t = threadIdx.x;
    const int lane = t & 63, wid = t >> 6;
    const int wm = wid & 1, wn = wid >> 1;
    const int lr = lane & 15, kg = lane >> 4;

    f32x4 acc[4][8] = {};

    const int srow = t >> 2;
    const int cgl = t & 3;
    const int gcg = (cgl ^ ((srow >> 1) & 3)) * 8;
    const int scg = (kg ^ ((lr >> 1) & 3)) * 8;

    const bf16* Qrow0 = Qb + (size_t)(by * 128 + srow) * EE + gcg;
    const bf16* Krow0 = Kb + (size_t)(bxp * 256 + srow) * EE + gcg;

    auto stage = [&](int k, int b) {
        const int k0 = k * 32;
#pragma unroll
        for (int i = 0; i < 2; ++i)
            GLOAD_LDS16(Qrow0 + (size_t)(64 * i) * EE + k0, &sm.st.A[b][srow + 64 * i][cgl * 8]);
#pragma unroll
        for (int i = 0; i < 4; ++i)
            GLOAD_LDS16(Krow0 + (size_t)(64 * i) * EE + k0, &sm.st.B[b][srow + 64 * i][cgl * 8]);
    };
    auto compute = [&](int b) {
        bf16x8 af[4], bfr[8];
#pragma unroll
        for (int im = 0; im < 4; ++im)
            af[im] = *(const bf16x8*)&sm.st.A[b][wm * 64 + im * 16 + lr][scg];
#pragma unroll
        for (int in = 0; in < 8; ++in)
            bfr[in] = *(const bf16x8*)&sm.st.B[b][wn * 128 + in * 16 + lr][scg];
#pragma unroll
        for (int im = 0; im < 4; ++im)
#pragma unroll
            for (int in = 0; in < 8; ++in)
                acc[im][in] = mfma16(af[im], bfr[in], acc[im][in]);
    };

    stage(0, 0);
#pragma unroll
    for (int k = 0; k < 16; ++k) {
        __builtin_amdgcn_s_waitcnt(0);
        __syncthreads();
        if (k < 15) stage(k + 1, (k + 1) & 1);
        compute(k & 1);
    }
    __syncthreads();

    const float inv_scale = 0.011048543456039806f;  // 1/(4*sqrt(512))
#pragma unroll
    for (int pph = 0; pph < 2; ++pph) {
        if (wm == pph) {
#pragma unroll
            for (int im = 0; im < 4; ++im) {
                const int row = im * 16 + kg * 4;
#pragma unroll
                for (int in = 0; in < 8; ++in) {
                    const int col = wn * 128 + in * 16 + lr;
#pragma unroll
                    for (int r = 0; r < 4; ++r)
                        sm.ep[row + r][col] = (f16)(acc[im][in][r] * inv_scale);
                }
            }
        }
        __syncthreads();
#pragma unroll
        for (int i = 0; i < 8; ++i) {
            const int c = i * 256 + t;
            const int row = c >> 5, colg = (c & 31) * 8;
            *(uint4*)(Sb + (size_t)(by * 128 + pph * 64 + row) * LL + bxp * 256 + colg) =
                *(const uint4*)&sm.ep[row][colg];
        }
        __syncthreads();
    }
}

// ---------------------------------------------------------------------------
// Row softmax (1024 cols, f16 in) over 8 batches, mean, write one quadrant.
// No max-subtraction: |S| small (sigma ~0.25), exp is exact-safe in fp32.
// grid (1024, 4): x = q row, y = map.
// ---------------------------------------------------------------------------
struct SmParams {
    const f16* s[4];
};

__global__ __launch_bounds__(256) void softmax_mean_kernel(SmParams p, float* __restrict__ out) {
    const int q = blockIdx.x;
    const int map = blockIdx.y;
    const f16* __restrict__ S = p.s[map];
    const int t = threadIdx.x;
    const int lane = t & 63, wid = t >> 6;
    __shared__ float red[NBATCH][4];

    f16x4 v[NBATCH];
#pragma unroll
    for (int n = 0; n < NBATCH; ++n)
        v[n] = *(const f16x4*)(S + ((size_t)n * LL + q) * LL + t * 4);

    float e[NBATCH][4];
#pragma unroll
    for (int n = 0; n < NBATCH; ++n) {
        float s = 0.f;
#pragma unroll
        for (int j = 0; j < 4; ++j) {
            e[n][j] = __expf((float)v[n][j]);
            s += e[n][j];
        }
#pragma unroll
        for (int off = 32; off; off >>= 1) s += __shfl_xor(s, off);
        if (lane == 0) red[n][wid] = s;
    }
    __syncthreads();

    float acc[4] = {};
#pragma unroll
    for (int n = 0; n < NBATCH; ++n) {
        const float inv = 1.0f / (red[n][0] + red[n][1] + red[n][2] + red[n][3]);
#pragma unroll
        for (int j = 0; j < 4; ++j) acc[j] += e[n][j] * inv;
    }

    const int orow = (map >= 2 ? LL : 0) + q;
    const int ocol = (map & 1 ? LL : 0) + t * 4;
    float4 o = make_float4(acc[0] * 0.125f, acc[1] * 0.125f, acc[2] * 0.125f, acc[3] * 0.125f);
    *(float4*)(out + (size_t)orow * (2 * LL) + ocol) = o;
}

// ---------------------------------------------------------------------------
extern "C" void kernel_launch(void* const* d_in, const int* in_sizes, int n_in,
                              void* d_out, int out_size, void* d_ws, size_t ws_size,
                              hipStream_t stream) {
    const float* modalA = (const float*)d_in[0];
    const float* modalB = (const float*)d_in[1];
    const float* WqA = (const float*)d_in[2];
    const float* bqA = (const float*)d_in[3];
    const float* WkA = (const float*)d_in[4];
    const float* bkA = (const float*)d_in[5];
    const float* WqB = (const float*)d_in[6];
    const float* bqB = (const float*)d_in[7];
    const float* WkB = (const float*)d_in[8];
    const float* bkB = (const float*)d_in[9];
    float* out = (float*)d_out;

    // ws layout (~100.7 MB):
    //   [qk: 4 x 8192x512 bf16 = 33.55 MB]
    //   [region2: XA/XB/W4 bf16 (18.9 MB) then reused by S[4] f16 (67.1 MB)]
    const size_t projN = (size_t)(NBATCH * LL) * EE;       // 4 Mi elems
    const size_t mapN = (size_t)NBATCH * LL * LL;          // 8 Mi elems per map
    char* base = (char*)d_ws;
    bf16* qk = (bf16*)base;
    char* region2 = base + 4 * projN * sizeof(bf16);
    bf16* XA = (bf16*)region2;
    bf16* XB = XA + projN;
    bf16* W4 = XB + projN;                                  // 4 x 512x512
    f16* S = (f16*)region2;

    CvtParams cp;
    cp.src[0] = modalA; cp.dst[0] = XA; cp.n4[0] = (int)(projN / 4);
    cp.src[1] = modalB; cp.dst[1] = XB; cp.n4[1] = (int)(projN / 4);
    const float* wsrc[4] = {WqA, WkA, WqB, WkB};
    for (int i = 0; i < 4; ++i) {
        cp.src[2 + i] = wsrc[i];
        cp.dst[2 + i] = W4 + (size_t)i * EE * EE;
        cp.n4[2 + i] = EE * EE / 4;
    }
    cvt_kernel<<<dim3(512, 6), 256, 0, stream>>>(cp);

    ProjParams pp;
    pp.x[0] = XA; pp.x[1] = XA; pp.x[2] = XB; pp.x[3] = XB;
    for (int i = 0; i < 4; ++i) pp.w[i] = W4 + (size_t)i * EE * EE;
    pp.b[0] = bqA; pp.b[1] = bkA; pp.b[2] = bqB; pp.b[3] = bkB;
    proj_kernel<<<dim3(512), 256, 0, stream>>>(pp, qk);

    const bf16* qA = qk + 0 * projN;
    const bf16* kA = qk + 1 * projN;
    const bf16* qB = qk + 2 * projN;
    const bf16* kB = qk + 3 * projN;

    // map order: 0=(qA,kA)->TL, 1=(qA,kB)->TR, 2=(qB,kB)->BL, 3=(qB,kA)->BR
    ScoresParams sp;
    sp.q[0] = qA; sp.q[1] = qA; sp.q[2] = qB; sp.q[3] = qB;
    sp.k[0] = kA; sp.k[1] = kB; sp.k[2] = kB; sp.k[3] = kA;
    for (int m = 0; m < 4; ++m) sp.s[m] = S + (size_t)m * mapN;
    scores_kernel<<<dim3(1024), 256, 0, stream>>>(sp);

    SmParams smp;
    for (int m = 0; m < 4; ++m) smp.s[m] = S + (size_t)m * mapN;
    softmax_mean_kernel<<<dim3(1024, 4), 256, 0, stream>>>(smp, out);
}